// Round 1
// 363.987 us; speedup vs baseline: 1.1917x; 1.1917x over previous
//
#include <hip/hip_runtime.h>

// SOAM fused pipeline v2, MI355X gfx950. Structural change vs v1: C2 is never
// materialized in HBM. k1 computes only C1 (2MB). k3 recomputes its C2 tile from x
// via MFMA (the x read-set == the old C2 read-set, 64KB/block), keeps the fp32 C2
// residual in registers (MFMA1 output layout == epilogue layout, lane-for-lane),
// and writes out purely (no in-place read). This removes 128MB C2 write (k1),
// 114MB C2 fetch (k3), and the 16-way bank-conflicted staging loop
// (SQ_LDS_BANK_CONFLICT 3.4e7) entirely.
// B=8, C=64, H=W=256. Identity: R1==R2 => R3+R4 = (S1+S2)@R. Permutations
// i'=(i&3)*64+(i>>2), k^=(k&3)*64+(k>>2) applied to Ssum when writing it.
// ws: C1 fp32 [0,2M) | G fp32 [2M,6M) | Ssum2 bf16 [6M,7M).

#define EPS 1e-5f

typedef __attribute__((ext_vector_type(8))) short bf16x8;
typedef __attribute__((ext_vector_type(4))) float f32x4;

__device__ __forceinline__ unsigned short f2bf(float f){
  union { float f; unsigned int u; } a; a.f = f;
  return (unsigned short)((a.u + 0x7fffu + ((a.u >> 16) & 1u)) >> 16);
}
__device__ __forceinline__ float lrelu(float y){ return y >= 0.f ? y : 0.2f * y; }
__device__ __forceinline__ bf16x8 cvt8(const float* p){
  float4 a = *(const float4*)p;
  float4 b = *(const float4*)(p + 4);
  bf16x8 r;
  r[0] = (short)f2bf(a.x); r[1] = (short)f2bf(a.y); r[2] = (short)f2bf(a.z); r[3] = (short)f2bf(a.w);
  r[4] = (short)f2bf(b.x); r[5] = (short)f2bf(b.y); r[6] = (short)f2bf(b.z); r[7] = (short)f2bf(b.w);
  return r;
}

// ---------------- K1: C1 = lrelu(BN(x . w1)) only, pure streaming ----------------
// grid 512 (b*64 + tile), block 256, 4 positions (float4) per thread.
__global__ __launch_bounds__(256) void k1_c1(
    const float* __restrict__ x, const float* __restrict__ w1,
    const float* __restrict__ pb1, const float* __restrict__ pg1,
    const float* __restrict__ pbe1, const float* __restrict__ pm1,
    const float* __restrict__ pv1,
    float* __restrict__ C1)
{
  const int blk = blockIdx.x;
  const int b = blk >> 6;
  const int n0 = (blk & 63) << 10;
  const int t = threadIdx.x;
  __shared__ float w1s[64];
  if (t < 64) w1s[t] = w1[t];
  __syncthreads();
  const float* xb = x + ((size_t)b << 22);
  const int n = n0 + (t << 2);
  float4 d = {0.f, 0.f, 0.f, 0.f};
  #pragma unroll 8
  for (int c = 0; c < 64; c++){
    const float4 xv = *(const float4*)(xb + ((size_t)c << 16) + n);
    const float wv = w1s[c];
    d.x = fmaf(xv.x, wv, d.x); d.y = fmaf(xv.y, wv, d.y);
    d.z = fmaf(xv.z, wv, d.z); d.w = fmaf(xv.w, wv, d.w);
  }
  const float s1 = pg1[0] * rsqrtf(pv1[0] + EPS);
  const float t1 = (pb1[0] - pm1[0]) * s1 + pbe1[0];
  float4 o;
  o.x = lrelu(d.x * s1 + t1); o.y = lrelu(d.y * s1 + t1);
  o.z = lrelu(d.z * s1 + t1); o.w = lrelu(d.w * s1 + t1);
  *(float4*)(C1 + (b << 16) + n) = o;
}

// ---------------- K2a: Gram matrices G1 = C1 C1^T (rows), G2 = C1^T C1 (cols), fp32 ----------------
// grid 256: b(3b) | which(1b) | tile(4b); 64x64 tile per block, 4x4 micro-tile per thread.
__global__ __launch_bounds__(256) void k2_gram(const float* __restrict__ C1, float* __restrict__ G)
{
  const int bx = blockIdx.x;
  const int b = bx >> 5;
  const int which = (bx >> 4) & 1;
  const int tile = bx & 15;
  const int i0 = (tile >> 2) << 6, j0 = (tile & 3) << 6;
  const float* Cb = C1 + (b << 16);
  __shared__ float Al[32][68];
  __shared__ float Bl[32][68];
  const int t = threadIdx.x;
  const int tx = t & 15, ty = t >> 4;
  float acc[4][4];
  #pragma unroll
  for (int i = 0; i < 4; i++)
    #pragma unroll
    for (int j = 0; j < 4; j++) acc[i][j] = 0.f;

  for (int kc = 0; kc < 8; kc++){
    const int k0 = kc << 5;
    __syncthreads();
    if (which == 0){
      const int i = t & 63, kq = t >> 6;
      const float* pa = Cb + (i0 + i)*256 + k0 + kq*8;
      const float* pb = Cb + (j0 + i)*256 + k0 + kq*8;
      #pragma unroll
      for (int u = 0; u < 8; u++){ Al[kq*8+u][i] = pa[u]; Bl[kq*8+u][i] = pb[u]; }
    } else {
      const int k = t >> 3, i8 = (t & 7) << 3;
      const float* pa = Cb + (k0 + k)*256 + i0 + i8;
      const float* pb = Cb + (k0 + k)*256 + j0 + i8;
      *(float4*)&Al[k][i8]   = *(const float4*)pa;
      *(float4*)&Al[k][i8+4] = *(const float4*)(pa+4);
      *(float4*)&Bl[k][i8]   = *(const float4*)pb;
      *(float4*)&Bl[k][i8+4] = *(const float4*)(pb+4);
    }
    __syncthreads();
    #pragma unroll 4
    for (int k = 0; k < 32; k++){
      float4 a4 = *(const float4*)&Al[k][ty << 2];
      float4 b4 = *(const float4*)&Bl[k][tx << 2];
      float av[4] = {a4.x, a4.y, a4.z, a4.w};
      float bw[4] = {b4.x, b4.y, b4.z, b4.w};
      #pragma unroll
      for (int ii = 0; ii < 4; ii++)
        #pragma unroll
        for (int jj = 0; jj < 4; jj++)
          acc[ii][jj] = fmaf(av[ii], bw[jj], acc[ii][jj]);
    }
  }
  float* Go = G + ((size_t)(which*8 + b) << 16);
  #pragma unroll
  for (int r = 0; r < 4; r++){
    float4 o4 = {acc[r][0], acc[r][1], acc[r][2], acc[r][3]};
    *(float4*)&Go[(i0 + (ty<<2) + r)*256 + j0 + (tx<<2)] = o4;
  }
}

// ---------------- K2b: row softmax of G1,G2 -> S1,S2 (fp32, d_out) + permuted Ssum (bf16, ws) ----------------
__global__ __launch_bounds__(256) void k2_softmax(const float* __restrict__ G,
    float* __restrict__ S1o, float* __restrict__ S2o,
    unsigned short* __restrict__ Ssum2)
{
  const int bx = blockIdx.x;
  const int b = bx >> 8, i = bx & 255;
  const int j = threadIdx.x;
  const float v1 = G[((size_t)b << 16) + i*256 + j];
  const float v2 = G[((size_t)(8 + b) << 16) + i*256 + j];
  __shared__ float sm[4], sm2[4], ss[4], ss2[4];
  float a1 = v1, a2 = v2;
  #pragma unroll
  for (int off = 32; off > 0; off >>= 1){
    a1 = fmaxf(a1, __shfl_xor(a1, off));
    a2 = fmaxf(a2, __shfl_xor(a2, off));
  }
  const int wv = j >> 6;
  if ((j & 63) == 0){ sm[wv] = a1; sm2[wv] = a2; }
  __syncthreads();
  const float m1v = fmaxf(fmaxf(sm[0], sm[1]), fmaxf(sm[2], sm[3]));
  const float m2v = fmaxf(fmaxf(sm2[0], sm2[1]), fmaxf(sm2[2], sm2[3]));
  float e1 = __expf(v1 - m1v), e2 = __expf(v2 - m2v);
  float s1 = e1, s2 = e2;
  #pragma unroll
  for (int off = 32; off > 0; off >>= 1){
    s1 += __shfl_xor(s1, off);
    s2 += __shfl_xor(s2, off);
  }
  if ((j & 63) == 0){ ss[wv] = s1; ss2[wv] = s2; }
  __syncthreads();
  const float d1 = ss[0]+ss[1]+ss[2]+ss[3];
  const float d2 = ss2[0]+ss2[1]+ss2[2]+ss2[3];
  const float S1v = e1 / d1, S2v = e2 / d2;
  S1o[((size_t)b << 16) + i*256 + j] = S1v;
  S2o[((size_t)b << 16) + i*256 + j] = S2v;
  const int ip = ((i & 3) << 6) | (i >> 2);
  const int kp = ((j & 3) << 6) | (j >> 2);
  Ssum2[((size_t)b << 16) + ip*256 + kp] = f2bf(S1v + S2v);
}

// ---------------- K3: recompute C2 tile (MFMA) -> T' = Ssum2 @ R -> convO+BN+LReLU + C2 -> out ----------------
// grid 2048 (b*256 + jtile64), block 256. Pure-write on out; fp32 C2 residual lives in
// registers (MFMA1 D-layout (n=16nt+4q+r, o=16ot+m) == epilogue layout (stl,ct), lane-exact).
__global__ __launch_bounds__(256, 2) void k3_main(
    const float* __restrict__ x,
    const float* __restrict__ wA, const float* __restrict__ pbA,
    const float* __restrict__ pgA, const float* __restrict__ pbeA,
    const float* __restrict__ pmA, const float* __restrict__ pvA,
    const unsigned short* __restrict__ Ssum2,
    const float* __restrict__ wO, const float* __restrict__ pbO,
    const float* __restrict__ pgO, const float* __restrict__ pbeO,
    const float* __restrict__ pmO, const float* __restrict__ pvO,
    float* __restrict__ out)
{
  __shared__ unsigned short C2L[256][72];    // bf16 [s = band*64 + jl][c], +8 pad
  __shared__ unsigned short T_lds[256][72];  // bf16 [s][c_T]; wave-private 64-row slabs
  __shared__ float sAl[64], tAl[64], sOl[64], tOl[64];
  const int blk = blockIdx.x;
  const int b  = blk >> 8;
  const int j0 = (blk & 255) << 6;
  const int t = threadIdx.x;
  const int lane = t & 63, wv = t >> 6;
  const int m = lane & 15, q = lane >> 4;

  if (t < 64){
    const float sA = pgA[t] * rsqrtf(pvA[t] + EPS);
    sAl[t] = sA; tAl[t] = (pbA[t] - pmA[t]) * sA + pbeA[t];
    const float sO = pgO[t] * rsqrtf(pvO[t] + EPS);
    sOl[t] = sO; tOl[t] = (pbO[t] - pmO[t]) * sO + pbeO[t];
  }
  __syncthreads();

  float sAv[4], tAv[4];
  #pragma unroll
  for (int ot = 0; ot < 4; ot++){ sAv[ot] = sAl[16*ot + m]; tAv[ot] = tAl[16*ot + m]; }

  // wA B-frags: wA[o][c] fp32 -> bf16, lane col = o-local (m), 8 consecutive c
  bf16x8 wfrA[4][2];
  #pragma unroll
  for (int ot = 0; ot < 4; ot++)
    #pragma unroll
    for (int ks = 0; ks < 2; ks++)
      wfrA[ot][ks] = cvt8(wA + (16*ot + m)*64 + ks*32 + q*8);

  const f32x4 vzero = {0.f, 0.f, 0.f, 0.f};
  f32x4 c2r[4][4];   // [nt][ot] — becomes the fp32 C2 residual, held to the epilogue
  #pragma unroll
  for (int i = 0; i < 4; i++)
    #pragma unroll
    for (int j = 0; j < 4; j++) c2r[i][j] = vzero;

  // MFMA1: C2 pre-BN for band wv, positions jl = 16nt + ..., all 64 channels.
  // x addresses: per instr 16 lanes x 4B consecutive (m = w) => 64B segments, tile read once.
  const float* xb = x + ((size_t)b << 22) + (wv << 14) + j0;
  #pragma unroll
  for (int ks = 0; ks < 2; ks++)
    #pragma unroll
    for (int nt = 0; nt < 4; nt++){
      bf16x8 af;
      #pragma unroll
      for (int u = 0; u < 8; u++){
        const int cin = ks*32 + q*8 + u;
        af[u] = (short)f2bf(xb[((size_t)cin << 16) + 16*nt + m]);
      }
      #pragma unroll
      for (int ot = 0; ot < 4; ot++)
        c2r[nt][ot] = __builtin_amdgcn_mfma_f32_16x16x32_bf16(af, wfrA[ot][ks], c2r[nt][ot], 0, 0, 0);
    }

  // BN + LReLU in-place (fp32 residual) + bf16 copy into C2L for GEMM1.
  // Write banks: (144q + m/2) mod 128B-per-bank-pass => 2 lanes/bank per quarter-wave (free).
  #pragma unroll
  for (int nt = 0; nt < 4; nt++)
    #pragma unroll
    for (int ot = 0; ot < 4; ot++){
      #pragma unroll
      for (int r = 0; r < 4; r++){
        const float v = lrelu(c2r[nt][ot][r] * sAv[ot] + tAv[ot]);
        c2r[nt][ot][r] = v;
        C2L[64*wv + 16*nt + 4*q + r][16*ot + m] = f2bf(v);
      }
    }
  __syncthreads();

  // GEMM1: T'[i'][j] = sum_k^ Ssum2[i'][k^] * C2L[(k^>>6)*64 + jl][k^&63]
  const unsigned short* Sb = Ssum2 + ((size_t)b << 16);
  f32x4 accT[4][4];
  #pragma unroll
  for (int i = 0; i < 4; i++)
    #pragma unroll
    for (int j = 0; j < 4; j++) accT[i][j] = vzero;

  #pragma unroll
  for (int ks = 0; ks < 8; ks++){
    const int kk = ks*32 + q*8;
    const int rk = kk >> 6;
    const int c0 = kk & 63;
    bf16x8 af[4], bv[4];
    #pragma unroll
    for (int it = 0; it < 4; it++)
      af[it] = *(const bf16x8*)(Sb + (64*wv + 16*it + m)*256 + kk);
    #pragma unroll
    for (int jt = 0; jt < 4; jt++)
      bv[jt] = *(const bf16x8*)&C2L[(rk << 6) + 16*jt + m][c0];
    #pragma unroll
    for (int it = 0; it < 4; it++)
      #pragma unroll
      for (int jt = 0; jt < 4; jt++)
        accT[it][jt] = __builtin_amdgcn_mfma_f32_16x16x32_bf16(af[it], bv[jt], accT[it][jt], 0, 0, 0);
  }

  // T' -> LDS [s][c_T]; each wave's slab (rows 64wv..64wv+63) is produced and consumed
  // by the same wave => no barrier needed (compiler orders via lgkmcnt).
  #pragma unroll
  for (int it = 0; it < 4; it++)
    #pragma unroll
    for (int jt = 0; jt < 4; jt++){
      uint2 pk;
      pk.x = (unsigned)f2bf(accT[it][jt][0]) | ((unsigned)f2bf(accT[it][jt][1]) << 16);
      pk.y = (unsigned)f2bf(accT[it][jt][2]) | ((unsigned)f2bf(accT[it][jt][3]) << 16);
      *(uint2*)&T_lds[64*wv + 16*jt + m][16*it + 4*q] = pk;
    }

  // GEMM2: out_pre[s][cout] = sum_cT T[s][cT] * wO[cout][cT]
  bf16x8 wfrO[4][2];
  #pragma unroll
  for (int ct = 0; ct < 4; ct++)
    #pragma unroll
    for (int k2 = 0; k2 < 2; k2++)
      wfrO[ct][k2] = cvt8(wO + (16*ct + m)*64 + k2*32 + q*8);

  f32x4 acc2[4][4];
  #pragma unroll
  for (int i = 0; i < 4; i++)
    #pragma unroll
    for (int j = 0; j < 4; j++) acc2[i][j] = vzero;

  #pragma unroll
  for (int k2 = 0; k2 < 2; k2++)
    #pragma unroll
    for (int stl = 0; stl < 4; stl++){
      const bf16x8 afT = *(const bf16x8*)&T_lds[64*wv + 16*stl + m][k2*32 + q*8];
      #pragma unroll
      for (int ct = 0; ct < 4; ct++)
        acc2[stl][ct] = __builtin_amdgcn_mfma_f32_16x16x32_bf16(afT, wfrO[ct][k2], acc2[stl][ct], 0, 0, 0);
    }

  float sOv[4], tOv[4];
  #pragma unroll
  for (int ct = 0; ct < 4; ct++){ sOv[ct] = sOl[16*ct + m]; tOv[ct] = tOl[16*ct + m]; }

  // epilogue: out = C2 (regs) + lrelu(BN_O(acc2)); pure coalesced float4 store
  const size_t outB = ((size_t)b << 22);
  #pragma unroll
  for (int stl = 0; stl < 4; stl++)
    #pragma unroll
    for (int ct = 0; ct < 4; ct++){
      const int cout = 16*ct + m;
      const int ng0 = (wv << 14) + j0 + 16*stl + 4*q;
      float* po = out + outB + ((size_t)cout << 16) + ng0;
      float4 pk;
      pk.x = c2r[stl][ct][0] + lrelu(acc2[stl][ct][0] * sOv[ct] + tOv[ct]);
      pk.y = c2r[stl][ct][1] + lrelu(acc2[stl][ct][1] * sOv[ct] + tOv[ct]);
      pk.z = c2r[stl][ct][2] + lrelu(acc2[stl][ct][2] * sOv[ct] + tOv[ct]);
      pk.w = c2r[stl][ct][3] + lrelu(acc2[stl][ct][3] * sOv[ct] + tOv[ct]);
      *(float4*)po = pk;
    }
}

extern "C" void kernel_launch(void* const* d_in, const int* in_sizes, int n_in,
                              void* d_out, int out_size, void* d_ws, size_t ws_size,
                              hipStream_t stream) {
  const float* x   = (const float*)d_in[0];
  const float* w1  = (const float*)d_in[1];
  const float* b1  = (const float*)d_in[2];
  const float* g1  = (const float*)d_in[3];
  const float* be1 = (const float*)d_in[4];
  const float* m1  = (const float*)d_in[5];
  const float* v1  = (const float*)d_in[6];
  const float* wA  = (const float*)d_in[7];
  const float* bA  = (const float*)d_in[8];
  const float* gA  = (const float*)d_in[9];
  const float* beA = (const float*)d_in[10];
  const float* mA  = (const float*)d_in[11];
  const float* vA  = (const float*)d_in[12];
  const float* wO  = (const float*)d_in[13];
  const float* bO  = (const float*)d_in[14];
  const float* gO  = (const float*)d_in[15];
  const float* beO = (const float*)d_in[16];
  const float* mO  = (const float*)d_in[17];
  const float* vO  = (const float*)d_in[18];

  float* out = (float*)d_out;

  // ws layout (bytes): C1 fp32 [0,2M) | G fp32 [2M,6M) | Ssum2 bf16 [6M,7M)
  char* ws = (char*)d_ws;
  float* C1             = (float*)(ws);
  float* G              = (float*)(ws + (size_t)(2u << 20));
  unsigned short* Ssum2 = (unsigned short*)(ws + (size_t)(6u << 20));

  k1_c1<<<dim3(512), dim3(256), 0, stream>>>(x, w1, b1, g1, be1, m1, v1, C1);
  k2_gram<<<dim3(256), dim3(256), 0, stream>>>(C1, G);
  k2_softmax<<<dim3(2048), dim3(256), 0, stream>>>(G, out + 33554432u, out + 34078720u, Ssum2);
  k3_main<<<dim3(2048), dim3(256), 0, stream>>>(x, wA, bA, gA, beA, mA, vA, Ssum2,
                                                wO, bO, gO, beO, mO, vO, out);
}